// Round 9
// baseline (736.463 us; speedup 1.0000x reference)
//
#include <hip/hip_runtime.h>
#include <stdint.h>

typedef unsigned short u16;
typedef __attribute__((ext_vector_type(8))) short bf16x8;
typedef __attribute__((ext_vector_type(4))) float f32x4;
typedef __attribute__((ext_vector_type(2))) unsigned int u32x2;
typedef __attribute__((ext_vector_type(4))) unsigned int u32x4;

__device__ __forceinline__ float bf2f(u16 u) {
  union { unsigned int i; float f; } v; v.i = ((unsigned int)u) << 16; return v.f;
}
__device__ __forceinline__ u16 f2bf(float f) {
  union { float f; unsigned int i; } v; v.f = f;
  unsigned int x = v.i;
  return (u16)((x + 0x7fffu + ((x >> 16) & 1u)) >> 16);  // RNE
}

__device__ __forceinline__ void async16(const void* g, void* l) {
  __builtin_amdgcn_global_load_lds(
      (const __attribute__((address_space(1))) void*)g,
      (__attribute__((address_space(3))) void*)l, 16, 0, 0);
}

#define VMC6 asm volatile("s_waitcnt vmcnt(6)" ::: "memory")
#define VMC0 asm volatile("s_waitcnt vmcnt(0)" ::: "memory")
#define RAWBAR()                        \
  asm volatile("" ::: "memory");        \
  __builtin_amdgcn_s_barrier();         \
  asm volatile("" ::: "memory")

// ---------------------------------------------------------------- casts ----
__global__ __launch_bounds__(256) void cast_f32_to_bf16(
    const float* __restrict__ x, u16* __restrict__ y, long n) {
  long i = ((long)blockIdx.x * blockDim.x + threadIdx.x) * 8;
  long stride = (long)gridDim.x * blockDim.x * 8;
  for (long j = i; j < n; j += stride) {
    float4 a = ((const float4*)(x + j))[0];
    float4 b = ((const float4*)(x + j))[1];
    u32x4 o;
    o.x = (unsigned)f2bf(a.x) | ((unsigned)f2bf(a.y) << 16);
    o.y = (unsigned)f2bf(a.z) | ((unsigned)f2bf(a.w) << 16);
    o.z = (unsigned)f2bf(b.x) | ((unsigned)f2bf(b.y) << 16);
    o.w = (unsigned)f2bf(b.z) | ((unsigned)f2bf(b.w) << 16);
    __builtin_nontemporal_store(o, (u32x4*)(y + j));
  }
}

// key fp32 -> Kb bf16 [b,n,c] AND KbT bf16 [b,c,n]
__global__ __launch_bounds__(256) void castKT(
    const float* __restrict__ Kin, u16* __restrict__ Kb, u16* __restrict__ KbT) {
  __shared__ u16 tile[32][34];
  int t = threadIdx.x;
  long b = blockIdx.z;
  int n0 = blockIdx.x * 32, c0 = blockIdx.y * 32;
  int nr = t >> 3, c4 = (t & 7) * 4;
  float4 v = *(const float4*)(Kin + (b * 2048 + n0 + nr) * 512 + c0 + c4);
  unsigned q0 = f2bf(v.x), q1 = f2bf(v.y), q2 = f2bf(v.z), q3 = f2bf(v.w);
  u32x2 o1; o1.x = q0 | (q1 << 16); o1.y = q2 | (q3 << 16);
  __builtin_nontemporal_store(o1, (u32x2*)(Kb + (b * 2048 + n0 + nr) * 512 + c0 + c4));
  tile[nr][c4] = (u16)q0; tile[nr][c4 + 1] = (u16)q1;
  tile[nr][c4 + 2] = (u16)q2; tile[nr][c4 + 3] = (u16)q3;
  __syncthreads();
  int cr = t >> 3, n4 = (t & 7) * 4;
  unsigned r0 = tile[n4][cr], r1 = tile[n4 + 1][cr];
  unsigned r2 = tile[n4 + 2][cr], r3 = tile[n4 + 3][cr];
  u32x2 o2; o2.x = r0 | (r1 << 16); o2.y = r2 | (r3 << 16);
  __builtin_nontemporal_store(o2, (u32x2*)(KbT + (b * 512 + c0 + cr) * 2048 + n0 + n4));
}

// ------------------------------------------------- small weight kernels ----
__global__ __launch_bounds__(256) void smallGT(
    const float* __restrict__ Ai, const float* __restrict__ Bi, u16* __restrict__ C) {
  __shared__ float As[16][65], Bs[16][65];
  int t = threadIdx.x;
  int i0 = blockIdx.y * 16, j0 = blockIdx.x * 16;
  int r = t >> 4, c4 = (t & 15) * 4;
  int ty = t >> 4, tx = t & 15;
  float acc = 0.f;
  for (int d0 = 0; d0 < 512; d0 += 64) {
    float4 a = *(const float4*)(Ai + (i0 + r) * 512 + d0 + c4);
    float4 b = *(const float4*)(Bi + (j0 + r) * 512 + d0 + c4);
    __syncthreads();
    As[r][c4] = a.x; As[r][c4 + 1] = a.y; As[r][c4 + 2] = a.z; As[r][c4 + 3] = a.w;
    Bs[r][c4] = b.x; Bs[r][c4 + 1] = b.y; Bs[r][c4 + 2] = b.z; Bs[r][c4 + 3] = b.w;
    __syncthreads();
#pragma unroll
    for (int d = 0; d < 64; ++d) acc += As[ty][d] * Bs[tx][d];
  }
  C[(i0 + ty) * 512 + j0 + tx] = f2bf(acc);
}

__global__ __launch_bounds__(256) void smallW2T(
    const float* __restrict__ Wv, const float* __restrict__ Wo, u16* __restrict__ C) {
  __shared__ float Vs[16][65];
  __shared__ float Os[64][17];
  int t = threadIdx.x;
  int k0 = blockIdx.x * 16, n0 = blockIdx.y * 16;
  int r = t >> 4, c4 = (t & 15) * 4;
  int dd = t >> 2, nn4 = (t & 3) * 4;
  int ty = t >> 4, tx = t & 15;
  float acc = 0.f;
  for (int d0 = 0; d0 < 512; d0 += 64) {
    float4 a = *(const float4*)(Wv + (k0 + r) * 512 + d0 + c4);
    float4 b = *(const float4*)(Wo + (long)(d0 + dd) * 512 + n0 + nn4);
    __syncthreads();
    Vs[r][c4] = a.x; Vs[r][c4 + 1] = a.y; Vs[r][c4 + 2] = a.z; Vs[r][c4 + 3] = a.w;
    Os[dd][nn4] = b.x; Os[dd][nn4 + 1] = b.y; Os[dd][nn4 + 2] = b.z; Os[dd][nn4 + 3] = b.w;
    __syncthreads();
#pragma unroll
    for (int d = 0; d < 64; ++d) acc += Vs[tx][d] * Os[d][ty];
  }
  C[(n0 + ty) * 512 + k0 + tx] = f2bf(acc);
}

__global__ __launch_bounds__(256) void wveck(
    const float* __restrict__ Wk, const float* __restrict__ bq, float* __restrict__ wv) {
  int c = blockIdx.x, t = threadIdx.x;
  float s = 0.f;
  for (int d = t; d < 512; d += 256) s += Wk[c * 512 + d] * bq[d];
  for (int off = 32; off; off >>= 1) s += __shfl_xor(s, off);
  __shared__ float r4[4];
  if ((t & 63) == 0) r4[t >> 6] = s;
  __syncthreads();
  if (t == 0) wv[c] = (r4[0] + r4[1] + r4[2] + r4[3]) * (1.0f / 512.0f);
}

__global__ __launch_bounds__(256) void cveck(
    const float* __restrict__ Wo, const float* __restrict__ bv,
    const float* __restrict__ bo, float* __restrict__ c2) {
  int e = blockIdx.x * 256 + threadIdx.x;
  float s = 0.f;
  for (int d = 0; d < 512; ++d) s += bv[d] * Wo[d * 512 + e];
  c2[e] = s * (1.0f / 2048.0f) + bo[e];
}

__global__ __launch_bounds__(256) void betak(
    const u16* __restrict__ Kb, const float* __restrict__ wv, float* __restrict__ beta) {
  __shared__ float ws[512];
  int t = threadIdx.x, lane = t & 63, wid = t >> 6;
  ws[t] = wv[t];
  ws[t + 256] = wv[t + 256];
  __syncthreads();
  long row = (long)blockIdx.x * 4 + wid;
  bf16x8 v = *(const bf16x8*)(Kb + row * 512 + lane * 8);
  float s = 0.f;
#pragma unroll
  for (int j = 0; j < 8; ++j) s += bf2f((u16)v[j]) * ws[lane * 8 + j];
  for (int off = 32; off; off >>= 1) s += __shfl_xor(s, off);
  if (lane == 0) beta[row] = s;
}

// rinv[r] = 1 / sum_{j<32} psum[r*32+j]
__global__ __launch_bounds__(256) void rowred(
    const float* __restrict__ psum, float* __restrict__ rinv, int nrows) {
  int r = blockIdx.x * 256 + threadIdx.x;
  if (r >= nrows) return;
  const float* p = psum + (long)r * 32;
  float s = 0.f;
#pragma unroll
  for (int j = 0; j < 32; ++j) s += p[j];
  rinv[r] = 1.0f / s;
}

// --------------------------------------------------- 256x128 4-wave gemm ----
// C[m,n] = scale*sum_k A[m,k]*B[n,k]; ring-of-3 LDS slots (24 KiB each),
// ONE raw s_barrier per K-tile, counted vmcnt(6): tile t+1's staging stays in
// flight across the barrier (prefetch distance 2 > HBM latency). Stage is
// issued AFTER the barrier (WAR-safe: slot (t+2)%3 was last read before the
// previous barrier). XCD-pinned decode (Z%8==0) keeps per-batch panels in one
// XCD L2. EXPO=1: epilogue computes exp(val) and deterministic partial row
// sums into psum[.][32]. rsc: per-row scale (PV normalization).
template <int MODE, int EXPO>
__global__ __launch_bounds__(256, 2) void gemm(
    const u16* __restrict__ A, const u16* __restrict__ B,
    const float* __restrict__ bias, long sBias,
    const float* __restrict__ rsc, float* __restrict__ psum,
    void* __restrict__ Cout,
    int N, int K, long sA, long sB, long sC, float scale,
    int mT, int nT, int Z, int nfast) {
  __shared__ __align__(16) char lds[3][24576];  // per slot: A 16K | B 8K
  const int t = threadIdx.x;
  const int lane = t & 63;
  const int w = t >> 6;        // 0..3
  const int wm = w >> 1;       // 0..1 (row half)
  const int wn = w & 1;        // 0..1 (col half)

  // ---- block decode ----
  const int wg = blockIdx.x;
  const int nb = mT * nT;
  long z; int within;
  if (Z > 1 && (Z & 7) == 0) {
    int xcd = wg & 7;
    int sub = wg >> 3;
    z = (long)(sub / nb) * 8 + xcd;
    within = sub % nb;
  } else {
    z = wg / nb;
    within = wg % nb;
  }
  int bx, by;
  if (nfast) { by = within % nT; bx = within / nT; }
  else       { bx = within % mT; by = within / mT; }
  const long m0 = (long)bx * 256;
  const int n0 = by * 128;
  const int nt = K >> 5;       // >= 16 at all call sites

  // staging: linear LDS dest, inverse-swizzled global source
  const int srow = w * 16 + (lane >> 2);                  // 0..63
  const int koff = 8 * ((lane & 3) ^ ((lane >> 3) & 3));  // elems
  const u16* pa = A + z * sA + (m0 + srow) * (long)K + koff;
  const u16* pb = B + z * sB + ((long)(n0 + srow)) * K + koff;
  const int ldsW = w * 1024;   // wave-uniform

  // reads: swizzled ds_read_b128
  const int fr = lane & 15;
  const int kb = (lane >> 4) * 16;
  const int sw = ((fr >> 1) & 3) << 4;
  const int aoff = (wm * 128 + fr) * 64 + (kb ^ sw);        // + mi*1024
  const int boff = 16384 + (wn * 64 + fr) * 64 + (kb ^ sw); // + ni*1024

  f32x4 acc[8][4] = {};

#define STAGE(SLOT)                                                        \
  do {                                                                     \
    char* d_ = lds[SLOT] + ldsW;                                           \
    _Pragma("unroll") for (int c = 0; c < 4; ++c)                          \
        async16(pa + (long)c * 64 * K, d_ + c * 4096);                     \
    _Pragma("unroll") for (int c = 0; c < 2; ++c)                          \
        async16(pb + (long)c * 64 * K, d_ + 16384 + c * 4096);             \
    pa += 32; pb += 32;                                                    \
  } while (0)

  // prologue: stage tiles 0,1 into slots 0,1 (12 loads outstanding)
  STAGE(0);
  STAGE(1);

  int slot = 0, stslot = 2;
  for (int tt = 0; tt < nt; ++tt) {
    if (tt < nt - 1) { VMC6; } else { VMC0; }   // oldest tile's 6 loads done
    RAWBAR();                                    // no vmcnt(0) drain here
    if (tt + 2 < nt) {
      STAGE(stslot);
      stslot = (stslot == 2) ? 0 : stslot + 1;
    }
    const char* rb = lds[slot];
    bf16x8 bf[4];
#pragma unroll
    for (int ni = 0; ni < 4; ++ni)
      bf[ni] = *(const bf16x8*)(rb + boff + ni * 1024);
    __builtin_amdgcn_s_setprio(1);
#pragma unroll
    for (int mi = 0; mi < 8; ++mi) {
      bf16x8 af = *(const bf16x8*)(rb + aoff + mi * 1024);
#pragma unroll
      for (int ni = 0; ni < 4; ++ni)
        acc[mi][ni] = __builtin_amdgcn_mfma_f32_16x16x32_bf16(af, bf[ni], acc[mi][ni], 0, 0, 0);
    }
    __builtin_amdgcn_s_setprio(0);
    slot = (slot == 2) ? 0 : slot + 1;
  }
#undef STAGE

  // ---- epilogue ----
  const int er = (lane >> 4) * 4;
  const int ec = lane & 15;
  float bvv[4];
#pragma unroll
  for (int ni = 0; ni < 4; ++ni)
    bvv[ni] = bias ? bias[z * sBias + n0 + wn * 64 + ni * 16 + ec] : 0.0f;
  if (MODE == 0) {
    // bf16 coalesced via LDS transpose: 2 passes x 128 rows, stride 136 u16
    u16* Ep = (u16*)lds;
    u16* Cp = (u16*)Cout + z * sC;
#pragma unroll
    for (int p = 0; p < 2; ++p) {
      __syncthreads();
      if (wm == p) {
#pragma unroll
        for (int mi = 0; mi < 8; ++mi) {
#pragma unroll
          for (int i = 0; i < 4; ++i) {
            int lrow = mi * 16 + er + i;  // 0..127 within this wm half
            float rv = 1.0f;
            if (!EXPO && rsc) rv = rsc[z * 2048 + m0 + wm * 128 + lrow];
            float rs = 0.f;
#pragma unroll
            for (int ni = 0; ni < 4; ++ni) {
              float val = acc[mi][ni][i] * scale + bvv[ni];
              if (EXPO) { val = __expf(val); rs += val; }
              else val *= rv;
              Ep[lrow * 136 + wn * 64 + ni * 16 + ec] = f2bf(val);
            }
            if (EXPO) {
              rs += __shfl_xor(rs, 1);
              rs += __shfl_xor(rs, 2);
              rs += __shfl_xor(rs, 4);
              rs += __shfl_xor(rs, 8);
              if (ec == 0)
                psum[((long)z * 2048 + m0 + wm * 128 + lrow) * 32 + by * 2 + wn] = rs;
            }
          }
        }
      }
      __syncthreads();
#pragma unroll
      for (int s = 0; s < 8; ++s) {
        int idx = s * 256 + t;
        int R = idx >> 4;   // 0..127
        int j = idx & 15;
        u32x4 d = *(const u32x4*)(Ep + R * 136 + j * 8);
        *(u32x4*)(Cp + (m0 + p * 128 + R) * (long)N + n0 + j * 8) = d;
      }
    }
  } else {
    // fp32 coalesced via LDS transpose: 4 passes x 64 rows, stride 132 f32
    float* Ep = (float*)lds;
    float* Cp = (float*)Cout + z * sC;
#pragma unroll
    for (int p = 0; p < 4; ++p) {
      __syncthreads();
      if (wm == (p >> 1)) {
#pragma unroll
        for (int mi2 = 0; mi2 < 4; ++mi2) {
          int mi = (p & 1) * 4 + mi2;
#pragma unroll
          for (int ni = 0; ni < 4; ++ni)
#pragma unroll
            for (int i = 0; i < 4; ++i)
              Ep[(mi2 * 16 + er + i) * 132 + wn * 64 + ni * 16 + ec] =
                  acc[mi][ni][i] * scale + bvv[ni];
        }
      }
      __syncthreads();
#pragma unroll
      for (int s = 0; s < 8; ++s) {
        int idx = s * 256 + t;
        int R = idx >> 5;   // 0..63
        int j = idx & 31;   // 0..31
        f32x4 d = *(const f32x4*)(Ep + R * 132 + j * 4);
        __builtin_nontemporal_store(
            d, (f32x4*)(Cp + (m0 + p * 64 + R) * (long)N + n0 + j * 4));
      }
    }
  }
}

// -------------------------------------------------------------- launch ----
extern "C" void kernel_launch(void* const* d_in, const int* in_sizes, int n_in,
                              void* d_out, int out_size, void* d_ws, size_t ws_size,
                              hipStream_t stream) {
  const float* query = (const float*)d_in[0];
  const float* key_  = (const float*)d_in[1];
  const float* Wq = (const float*)d_in[2];
  const float* bq = (const float*)d_in[3];
  const float* Wk = (const float*)d_in[4];
  const float* bk = (const float*)d_in[5];  // row-constant in scores: cancels
  const float* Wv = (const float*)d_in[6];
  const float* bv = (const float*)d_in[7];
  const float* Wo = (const float*)d_in[8];
  const float* bo = (const float*)d_in[9];
  (void)bk;
  float* out = (float*)d_out;

  const long tokE = 65536L * 512;
  const long bstride = 2048L * 512;

  char* ws = (char*)d_ws;
  u16* Qb   = (u16*)(ws);                     // 64 MB (reused as attn)
  u16* Kb   = (u16*)(ws + 67108864L);         // 64 MB
  u16* KbT  = (u16*)(ws + 134217728L);        // 64 MB
  u16* GT   = (u16*)(ws + 201326592L);        // 0.5 MB
  u16* W2T  = (u16*)(ws + 201850880L);        // 0.5 MB
  float* wv   = (float*)(ws + 202375168L);    // 2 KB
  float* c2   = (float*)(ws + 202377216L);    // 2 KB
  float* beta = (float*)(ws + 202379264L);    // 256 KB
  float* rinv = (float*)(ws + 202641408L);    // 256 KB
  char* Sbase = ws + 203423744L;
  u16* attn = Qb;                             // Qb dead after q'-proj

  u16* qb = (u16*)d_out;                         // 64 MB scratch in d_out
  float* psum = (float*)((char*)d_out + 67108864L);  // up to 8 MB (g<=32)

  long s_avail = (long)ws_size - 203423744L;
  int g = (int)(s_avail / 8388608L);
  if (g < 1) g = 1;
  if (g > 32) g = 32;
  if (g >= 8) g &= ~7;  // keep batches-per-dispatch a multiple of 8 (XCD pin)

  // 1. casts + fused weights
  cast_f32_to_bf16<<<16384, 256, 0, stream>>>(query, Qb, tokE);
  castKT<<<dim3(64, 16, 32), 256, 0, stream>>>(key_, Kb, KbT);
  smallGT<<<dim3(32, 32), 256, 0, stream>>>(Wk, Wq, GT);    // GT[n,c]
  smallW2T<<<dim3(32, 32), 256, 0, stream>>>(Wv, Wo, W2T);  // W2T[e,k]
  wveck<<<512, 256, 0, stream>>>(Wk, bq, wv);
  cveck<<<2, 256, 0, stream>>>(Wo, bv, bo, c2);
  betak<<<16384, 256, 0, stream>>>(Kb, wv, beta);

  // 2. q' = Q @ (Wq Wk^T)   [65536 x 512]
  gemm<0, 0><<<256 * 4, 256, 0, stream>>>(Qb, GT, nullptr, 0, nullptr, nullptr,
                                          qb, 512, 512, 0, 0, 0, 1.0f, 256, 4, 1, 0);

  // 3. attention per group:
  //    E = exp(q'.Kin^T/512 + beta) (+ row partials) ; rinv = 1/rowsum ;
  //    T = E.Kin * rinv / 2048
  for (int b0 = 0; b0 < 32; b0 += g) {
    int bc = (32 - b0 < g) ? (32 - b0) : g;
    u16* Sg = (u16*)Sbase;
    gemm<0, 1><<<8 * 16 * bc, 256, 0, stream>>>(
        qb + (long)b0 * bstride, Kb + (long)b0 * bstride,
        beta + (long)b0 * 2048, 2048, nullptr, psum, Sg, 2048, 512,
        bstride, bstride, 2048L * 2048, 1.0f / 512.0f, 8, 16, bc, 0);
    rowred<<<(bc * 2048 + 255) / 256, 256, 0, stream>>>(psum, rinv + b0 * 2048,
                                                        bc * 2048);
    gemm<0, 0><<<8 * 4 * bc, 256, 0, stream>>>(
        Sg, KbT + (long)b0 * bstride, nullptr, 0, rinv + b0 * 2048, nullptr,
        attn + (long)b0 * bstride, 512, 2048,
        2048L * 2048, bstride, bstride, 1.0f / 2048.0f, 8, 4, bc, 1);
  }

  // 4. out = T @ (Wv Wo) + c2   (fp32)
  gemm<2, 0><<<256 * 4, 256, 0, stream>>>(attn, W2T, c2, 0, nullptr, nullptr,
                                          out, 512, 512, 0, 0, 0, 1.0f, 256, 4, 1, 0);
}

// Round 10
// 678.752 us; speedup vs baseline: 1.0850x; 1.0850x over previous
//
#include <hip/hip_runtime.h>
#include <stdint.h>

typedef unsigned short u16;
typedef __attribute__((ext_vector_type(8))) short bf16x8;
typedef __attribute__((ext_vector_type(4))) float f32x4;
typedef __attribute__((ext_vector_type(2))) unsigned int u32x2;
typedef __attribute__((ext_vector_type(4))) unsigned int u32x4;

__device__ __forceinline__ float bf2f(u16 u) {
  union { unsigned int i; float f; } v; v.i = ((unsigned int)u) << 16; return v.f;
}
__device__ __forceinline__ u16 f2bf(float f) {
  union { float f; unsigned int i; } v; v.f = f;
  unsigned int x = v.i;
  return (u16)((x + 0x7fffu + ((x >> 16) & 1u)) >> 16);  // RNE
}

__device__ __forceinline__ void async16(const void* g, void* l) {
  __builtin_amdgcn_global_load_lds(
      (const __attribute__((address_space(1))) void*)g,
      (__attribute__((address_space(3))) void*)l, 16, 0, 0);
}

#define VMC4 asm volatile("s_waitcnt vmcnt(4)" ::: "memory")
#define VMC0 asm volatile("s_waitcnt vmcnt(0)" ::: "memory")
#define RAWBAR()                        \
  asm volatile("" ::: "memory");        \
  __builtin_amdgcn_s_barrier();         \
  asm volatile("" ::: "memory")
#define LGKM0                                             \
  do {                                                    \
    asm volatile("s_waitcnt lgkmcnt(0)" ::: "memory");    \
    __builtin_amdgcn_sched_barrier(0);                    \
  } while (0)

#define DSR4(d, adr)                                                     \
  asm volatile("ds_read_b128 %0, %4 offset:0\n\t"                        \
               "ds_read_b128 %1, %4 offset:2048\n\t"                     \
               "ds_read_b128 %2, %4 offset:4096\n\t"                     \
               "ds_read_b128 %3, %4 offset:6144"                         \
               : "=&v"(d[0]), "=&v"(d[1]), "=&v"(d[2]), "=&v"(d[3])      \
               : "v"(adr))
#define DSR2(d, adr)                                                     \
  asm volatile("ds_read_b128 %0, %2 offset:0\n\t"                        \
               "ds_read_b128 %1, %2 offset:2048"                         \
               : "=&v"(d[0]), "=&v"(d[1])                                \
               : "v"(adr))

// ---------------------------------------------------------------- casts ----
__global__ __launch_bounds__(256) void cast_f32_to_bf16(
    const float* __restrict__ x, u16* __restrict__ y, long n) {
  long i = ((long)blockIdx.x * blockDim.x + threadIdx.x) * 8;
  long stride = (long)gridDim.x * blockDim.x * 8;
  for (long j = i; j < n; j += stride) {
    float4 a = ((const float4*)(x + j))[0];
    float4 b = ((const float4*)(x + j))[1];
    u32x4 o;
    o.x = (unsigned)f2bf(a.x) | ((unsigned)f2bf(a.y) << 16);
    o.y = (unsigned)f2bf(a.z) | ((unsigned)f2bf(a.w) << 16);
    o.z = (unsigned)f2bf(b.x) | ((unsigned)f2bf(b.y) << 16);
    o.w = (unsigned)f2bf(b.z) | ((unsigned)f2bf(b.w) << 16);
    __builtin_nontemporal_store(o, (u32x4*)(y + j));
  }
}

// key fp32 -> Kb bf16 [b,n,c] AND KbT bf16 [b,c,n]
__global__ __launch_bounds__(256) void castKT(
    const float* __restrict__ Kin, u16* __restrict__ Kb, u16* __restrict__ KbT) {
  __shared__ u16 tile[32][34];
  int t = threadIdx.x;
  long b = blockIdx.z;
  int n0 = blockIdx.x * 32, c0 = blockIdx.y * 32;
  int nr = t >> 3, c4 = (t & 7) * 4;
  float4 v = *(const float4*)(Kin + (b * 2048 + n0 + nr) * 512 + c0 + c4);
  unsigned q0 = f2bf(v.x), q1 = f2bf(v.y), q2 = f2bf(v.z), q3 = f2bf(v.w);
  u32x2 o1; o1.x = q0 | (q1 << 16); o1.y = q2 | (q3 << 16);
  __builtin_nontemporal_store(o1, (u32x2*)(Kb + (b * 2048 + n0 + nr) * 512 + c0 + c4));
  tile[nr][c4] = (u16)q0; tile[nr][c4 + 1] = (u16)q1;
  tile[nr][c4 + 2] = (u16)q2; tile[nr][c4 + 3] = (u16)q3;
  __syncthreads();
  int cr = t >> 3, n4 = (t & 7) * 4;
  unsigned r0 = tile[n4][cr], r1 = tile[n4 + 1][cr];
  unsigned r2 = tile[n4 + 2][cr], r3 = tile[n4 + 3][cr];
  u32x2 o2; o2.x = r0 | (r1 << 16); o2.y = r2 | (r3 << 16);
  __builtin_nontemporal_store(o2, (u32x2*)(KbT + (b * 512 + c0 + cr) * 2048 + n0 + n4));
}

// ------------------------------------------------- small weight kernels ----
__global__ __launch_bounds__(256) void smallGT(
    const float* __restrict__ Ai, const float* __restrict__ Bi, u16* __restrict__ C) {
  __shared__ float As[16][65], Bs[16][65];
  int t = threadIdx.x;
  int i0 = blockIdx.y * 16, j0 = blockIdx.x * 16;
  int r = t >> 4, c4 = (t & 15) * 4;
  int ty = t >> 4, tx = t & 15;
  float acc = 0.f;
  for (int d0 = 0; d0 < 512; d0 += 64) {
    float4 a = *(const float4*)(Ai + (i0 + r) * 512 + d0 + c4);
    float4 b = *(const float4*)(Bi + (j0 + r) * 512 + d0 + c4);
    __syncthreads();
    As[r][c4] = a.x; As[r][c4 + 1] = a.y; As[r][c4 + 2] = a.z; As[r][c4 + 3] = a.w;
    Bs[r][c4] = b.x; Bs[r][c4 + 1] = b.y; Bs[r][c4 + 2] = b.z; Bs[r][c4 + 3] = b.w;
    __syncthreads();
#pragma unroll
    for (int d = 0; d < 64; ++d) acc += As[ty][d] * Bs[tx][d];
  }
  C[(i0 + ty) * 512 + j0 + tx] = f2bf(acc);
}

__global__ __launch_bounds__(256) void smallW2T(
    const float* __restrict__ Wv, const float* __restrict__ Wo, u16* __restrict__ C) {
  __shared__ float Vs[16][65];
  __shared__ float Os[64][17];
  int t = threadIdx.x;
  int k0 = blockIdx.x * 16, n0 = blockIdx.y * 16;
  int r = t >> 4, c4 = (t & 15) * 4;
  int dd = t >> 2, nn4 = (t & 3) * 4;
  int ty = t >> 4, tx = t & 15;
  float acc = 0.f;
  for (int d0 = 0; d0 < 512; d0 += 64) {
    float4 a = *(const float4*)(Wv + (k0 + r) * 512 + d0 + c4);
    float4 b = *(const float4*)(Wo + (long)(d0 + dd) * 512 + n0 + nn4);
    __syncthreads();
    Vs[r][c4] = a.x; Vs[r][c4 + 1] = a.y; Vs[r][c4 + 2] = a.z; Vs[r][c4 + 3] = a.w;
    Os[dd][nn4] = b.x; Os[dd][nn4 + 1] = b.y; Os[dd][nn4 + 2] = b.z; Os[dd][nn4 + 3] = b.w;
    __syncthreads();
#pragma unroll
    for (int d = 0; d < 64; ++d) acc += Vs[tx][d] * Os[d][ty];
  }
  C[(n0 + ty) * 512 + k0 + tx] = f2bf(acc);
}

__global__ __launch_bounds__(256) void wveck(
    const float* __restrict__ Wk, const float* __restrict__ bq, float* __restrict__ wv) {
  int c = blockIdx.x, t = threadIdx.x;
  float s = 0.f;
  for (int d = t; d < 512; d += 256) s += Wk[c * 512 + d] * bq[d];
  for (int off = 32; off; off >>= 1) s += __shfl_xor(s, off);
  __shared__ float r4[4];
  if ((t & 63) == 0) r4[t >> 6] = s;
  __syncthreads();
  if (t == 0) wv[c] = (r4[0] + r4[1] + r4[2] + r4[3]) * (1.0f / 512.0f);
}

__global__ __launch_bounds__(256) void cveck(
    const float* __restrict__ Wo, const float* __restrict__ bv,
    const float* __restrict__ bo, float* __restrict__ c2) {
  int e = blockIdx.x * 256 + threadIdx.x;
  float s = 0.f;
  for (int d = 0; d < 512; ++d) s += bv[d] * Wo[d * 512 + e];
  c2[e] = s * (1.0f / 2048.0f) + bo[e];
}

__global__ __launch_bounds__(256) void betak(
    const u16* __restrict__ Kb, const float* __restrict__ wv, float* __restrict__ beta) {
  __shared__ float ws[512];
  int t = threadIdx.x, lane = t & 63, wid = t >> 6;
  ws[t] = wv[t];
  ws[t + 256] = wv[t + 256];
  __syncthreads();
  long row = (long)blockIdx.x * 4 + wid;
  bf16x8 v = *(const bf16x8*)(Kb + row * 512 + lane * 8);
  float s = 0.f;
#pragma unroll
  for (int j = 0; j < 8; ++j) s += bf2f((u16)v[j]) * ws[lane * 8 + j];
  for (int off = 32; off; off >>= 1) s += __shfl_xor(s, off);
  if (lane == 0) beta[row] = s;
}

// rinv[r] = 1 / sum_{j<32} psum[r*32+j]
__global__ __launch_bounds__(256) void rowred(
    const float* __restrict__ psum, float* __restrict__ rinv, int nrows) {
  int r = blockIdx.x * 256 + threadIdx.x;
  if (r >= nrows) return;
  const float* p = psum + (long)r * 32;
  float s = 0.f;
#pragma unroll
  for (int j = 0; j < 32; ++j) s += p[j];
  rinv[r] = 1.0f / s;
}

// ----------------------------------------- 256x256 8-wave 8-phase gemm ----
// m201 template port. C[m,n] = scale*sum_k A[m,k]*B[n,k] (+bias) (Bt-form).
// BK=64, 2 LDS K-tile buffers (64 KiB each: A[256][64] | B[256][64]).
// 8 waves (2M x 4N), per-wave 128x64 out, acc[8][4] f32x4.
// Per iteration (2 K-tiles T,T+1): 8 phases, each {asm ds_read quadrant
// operands | stage 1 half-tile (2 gload_lds) -> s_barrier -> lgkmcnt(0)+
// sched_barrier -> setprio(1) 16 MFMA setprio(0) -> s_barrier}.
// Stagger: p1,p2: A(T+1); p3,p4: B(T+2); p5,p6: A(T+2); p7,p8: B(T+3).
// vmcnt(4) at p4/p8 (ledger: drains tile needed next, leaves newest half-
// tile pair in flight). Swizzle: 16B slot ^= (row&7) within 128B rows
// (<=2-way, free); inverse applied on gload source; LDS dest linear.
template <int MODE, int EXPO>
__global__ __launch_bounds__(512, 2) void gemm256(
    const u16* __restrict__ A, const u16* __restrict__ B,
    const float* __restrict__ bias, long sBias,
    const float* __restrict__ rsc, float* __restrict__ psum,
    void* __restrict__ Cout,
    int N, int K, long sA, long sB, long sC, float scale,
    int mT, int nT, int Z, int nfast) {
  __shared__ __align__(16) char lds[131072];
  const int t = threadIdx.x;
  const int lane = t & 63;
  const int w = t >> 6;        // 0..7
  const int wm = w >> 2;       // 0..1
  const int wn = w & 3;        // 0..3

  // ---- block decode (XCD pin when Z%8==0) ----
  const int wg = blockIdx.x;
  const int nb = mT * nT;
  long z; int within;
  if (Z > 1 && (Z & 7) == 0) {
    int xcd = wg & 7, sub = wg >> 3;
    z = (long)(sub / nb) * 8 + xcd;
    within = sub % nb;
  } else { z = wg / nb; within = wg % nb; }
  int bx, by;
  if (nfast) { by = within % nT; bx = within / nT; }
  else       { bx = within % mT; by = within / mT; }
  const long m0 = (long)bx * 256;
  const int n0 = by * 256;
  const int nt = K >> 6;       // K-tiles (BK=64); all call sites: even, >= 8
  const int niter = nt >> 1;

  // ---- staging geometry (inverse-swizzled source, linear LDS dest) ----
  const int srow = t >> 3;                      // 0..63 per instruction
  const int sslot = (t & 7) ^ (srow & 7);       // global 16B-slot
  const u16* pa = A + z * sA + (m0 + srow) * (long)K + sslot * 8;
  const u16* pb = B + z * sB + (n0 + srow) * (long)K + sslot * 8;
  const int sdst = t * 16;

  // ---- read geometry (swizzled asm ds_read_b128) ----
  const int fr = lane & 15;
  const int hi4 = lane >> 4;                    // 0..3
  const int s7 = fr & 7;
  const unsigned ldsb =
      (unsigned)(uintptr_t)(__attribute__((address_space(3))) char*)lds;
  const unsigned kc0 = (unsigned)(((hi4) ^ s7) * 16);
  const unsigned kc1 = (unsigned)(((4 + hi4) ^ s7) * 16);
  const unsigned arow = ldsb + (wm * 128 + fr) * 128;
  const unsigned brow = ldsb + 32768 + (wn * 64 + fr) * 128;

  bf16x8 a[2][4], b0[2][2], b1[2][2];
  f32x4 acc[8][4] = {};

#define STG_A(BUF, H, KT)                                        \
  do {                                                           \
    char* d_ = (char*)lds + (BUF) + (H) * 16384 + sdst;          \
    const u16* g_ = pa + (long)(KT) * 64 + (long)(H) * 128 * K;  \
    async16(g_, d_);                                             \
    async16(g_ + 64L * K, d_ + 8192);                            \
  } while (0)
#define STG_B(BUF, H, KT)                                        \
  do {                                                           \
    char* d_ = (char*)lds + (BUF) + 32768 + (H) * 16384 + sdst;  \
    const u16* g_ = pb + (long)(KT) * 64 + (long)(H) * 128 * K;  \
    async16(g_, d_);                                             \
    async16(g_ + 64L * K, d_ + 8192);                            \
  } while (0)
#define RD_A0(BUF) do { DSR4(a[0], arow + (BUF) + kc0); DSR4(a[1], arow + (BUF) + kc1); } while (0)
#define RD_A1(BUF) do { DSR4(a[0], arow + (BUF) + 8192 + kc0); DSR4(a[1], arow + (BUF) + 8192 + kc1); } while (0)
#define RD_B0(BUF) do { DSR2(b0[0], brow + (BUF) + kc0); DSR2(b0[1], brow + (BUF) + kc1); } while (0)
#define RD_B1(BUF) do { DSR2(b1[0], brow + (BUF) + 4096 + kc0); DSR2(b1[1], brow + (BUF) + 4096 + kc1); } while (0)
#define MF(Rb, Cb, Bs)                                                        \
  do {                                                                        \
    __builtin_amdgcn_s_setprio(1);                                            \
    _Pragma("unroll") for (int kk = 0; kk < 2; ++kk)                          \
    _Pragma("unroll") for (int mi = 0; mi < 4; ++mi)                          \
    _Pragma("unroll") for (int ni = 0; ni < 2; ++ni)                          \
        acc[(Rb) + mi][(Cb) + ni] = __builtin_amdgcn_mfma_f32_16x16x32_bf16(  \
            a[kk][mi], Bs[kk][ni], acc[(Rb) + mi][(Cb) + ni], 0, 0, 0);       \
    __builtin_amdgcn_s_setprio(0);                                            \
  } while (0)

  // ---- prologue: tile0 (all) -> buf0; tile1 B-halves -> buf1 ----
  STG_A(0, 0, 0); STG_A(0, 1, 0); STG_B(0, 0, 0); STG_B(0, 1, 0);
  STG_B(65536, 0, 1); STG_B(65536, 1, 1);
  VMC4;       // tile0's 8 loads drained; tile1 B (4) in flight
  RAWBAR();

  for (int it = 0; it < niter; ++it) {
    const int T = it * 2;
    const bool more = (it + 1 < niter);
    // p1: q(0,0) of tile T (buf0)
    RD_A0(0); RD_B0(0);
    STG_A(65536, 0, T + 1);
    RAWBAR(); LGKM0;
    MF(0, 0, b0);
    RAWBAR();
    // p2: q(0,1)
    RD_B1(0);
    STG_A(65536, 1, T + 1);
    RAWBAR(); LGKM0;
    MF(0, 2, b1);
    RAWBAR();
    // p3: q(1,1)
    RD_A1(0);
    if (more) STG_B(0, 0, T + 2);
    RAWBAR(); LGKM0;
    MF(4, 2, b1);
    RAWBAR();
    // p4: q(1,0) — no reads; vmcnt gate for tile T+1
    if (more) { STG_B(0, 1, T + 2); VMC4; } else { VMC0; }
    RAWBAR();
    MF(4, 0, b0);
    RAWBAR();
    // p5: q(0,0) of tile T+1 (buf1)
    RD_A0(65536); RD_B0(65536);
    if (more) STG_A(0, 0, T + 2);
    RAWBAR(); LGKM0;
    MF(0, 0, b0);
    RAWBAR();
    // p6: q(0,1)
    RD_B1(65536);
    if (more) STG_A(0, 1, T + 2);
    RAWBAR(); LGKM0;
    MF(0, 2, b1);
    RAWBAR();
    // p7: q(1,1)
    RD_A1(65536);
    if (more) STG_B(65536, 0, T + 3);
    RAWBAR(); LGKM0;
    MF(4, 2, b1);
    RAWBAR();
    // p8: q(1,0) — vmcnt gate for tile T+2
    if (more) { STG_B(65536, 1, T + 3); VMC4; }
    RAWBAR();
    MF(4, 0, b0);
    RAWBAR();
  }
#undef STG_A
#undef STG_B
#undef RD_A0
#undef RD_A1
#undef RD_B0
#undef RD_B1
#undef MF

  // ---- epilogue ----
  const int er = (lane >> 4) * 4;
  const int ec = lane & 15;
  float bvv[4];
#pragma unroll
  for (int ni = 0; ni < 4; ++ni)
    bvv[ni] = bias ? bias[z * sBias + n0 + wn * 64 + ni * 16 + ec] : 0.0f;
  if (MODE == 0) {
    // bf16 coalesced via LDS transpose: 2 passes x 128 rows, stride 264 u16
    u16* Ep = (u16*)lds;
    u16* Cp = (u16*)Cout + z * sC;
#pragma unroll
    for (int p = 0; p < 2; ++p) {
      __syncthreads();
      if (wm == p) {
#pragma unroll
        for (int mi = 0; mi < 8; ++mi) {
#pragma unroll
          for (int i = 0; i < 4; ++i) {
            int lrow = mi * 16 + er + i;
            float rv = 1.0f;
            if (!EXPO && rsc) rv = rsc[z * 2048 + m0 + wm * 128 + lrow];
            float rs = 0.f;
#pragma unroll
            for (int ni = 0; ni < 4; ++ni) {
              float val = acc[mi][ni][i] * scale + bvv[ni];
              if (EXPO) { val = __expf(val); rs += val; }
              else val *= rv;
              Ep[lrow * 264 + wn * 64 + ni * 16 + ec] = f2bf(val);
            }
            if (EXPO) {
              rs += __shfl_xor(rs, 1);
              rs += __shfl_xor(rs, 2);
              rs += __shfl_xor(rs, 4);
              rs += __shfl_xor(rs, 8);
              if (ec == 0)
                psum[((long)z * 2048 + m0 + wm * 128 + lrow) * 32 + by * 4 + wn] = rs;
            }
          }
        }
      }
      __syncthreads();
#pragma unroll
      for (int s = 0; s < 8; ++s) {
        int idx = s * 512 + t;
        int R = idx >> 5;   // 0..127
        int j = idx & 31;   // 0..31
        u32x4 d = *(const u32x4*)(Ep + R * 264 + j * 8);
        __builtin_nontemporal_store(
            d, (u32x4*)(Cp + (m0 + p * 128 + R) * (long)N + n0 + j * 8));
      }
    }
  } else {
    // fp32 coalesced via LDS transpose: 4 passes x 64 rows, stride 264 f32
    float* Ep = (float*)lds;
    float* Cp = (float*)Cout + z * sC;
#pragma unroll
    for (int p = 0; p < 4; ++p) {
      __syncthreads();
      if (wm == (p >> 1)) {
#pragma unroll
        for (int mi2 = 0; mi2 < 4; ++mi2) {
          int mi = (p & 1) * 4 + mi2;
#pragma unroll
          for (int ni = 0; ni < 4; ++ni)
#pragma unroll
            for (int i = 0; i < 4; ++i)
              Ep[(mi2 * 16 + er + i) * 264 + wn * 64 + ni * 16 + ec] =
                  acc[mi][ni][i] * scale + bvv[ni];
        }
      }
      __syncthreads();
#pragma unroll
      for (int s = 0; s < 8; ++s) {
        int idx = s * 512 + t;
        int R = idx >> 6;   // 0..63
        int j = idx & 63;   // 0..63
        f32x4 d = *(const f32x4*)(Ep + R * 264 + j * 4);
        __builtin_nontemporal_store(
            d, (f32x4*)(Cp + (m0 + p * 64 + R) * (long)N + n0 + j * 4));
      }
    }
  }
}

// -------------------------------------------------------------- launch ----
extern "C" void kernel_launch(void* const* d_in, const int* in_sizes, int n_in,
                              void* d_out, int out_size, void* d_ws, size_t ws_size,
                              hipStream_t stream) {
  const float* query = (const float*)d_in[0];
  const float* key_  = (const float*)d_in[1];
  const float* Wq = (const float*)d_in[2];
  const float* bq = (const float*)d_in[3];
  const float* Wk = (const float*)d_in[4];
  const float* bk = (const float*)d_in[5];  // row-constant in scores: cancels
  const float* Wv = (const float*)d_in[6];
  const float* bv = (const float*)d_in[7];
  const float* Wo = (const float*)d_in[8];
  const float* bo = (const float*)d_in[9];
  (void)bk;
  float* out = (float*)d_out;

  const long tokE = 65536L * 512;
  const long bstride = 2048L * 512;

  char* ws = (char*)d_ws;
  u16* Qb   = (u16*)(ws);                     // 64 MB (reused as attn)
  u16* Kb   = (u16*)(ws + 67108864L);         // 64 MB
  u16* KbT  = (u16*)(ws + 134217728L);        // 64 MB
  u16* GT   = (u16*)(ws + 201326592L);        // 0.5 MB
  u16* W2T  = (u16*)(ws + 201850880L);        // 0.5 MB
  float* wv   = (float*)(ws + 202375168L);    // 2 KB
  float* c2   = (float*)(ws + 202377216L);    // 2 KB
  float* beta = (float*)(ws + 202379264L);    // 256 KB
  float* rinv = (float*)(ws + 202641408L);    // 256 KB
  char* Sbase = ws + 203423744L;
  u16* attn = Qb;                             // Qb dead after q'-proj

  u16* qb = (u16*)d_out;                         // 64 MB scratch in d_out
  float* psum = (float*)((char*)d_out + 67108864L);  // 8 MB (consumed pre-outproj)

  long s_avail = (long)ws_size - 203423744L;
  int g = (int)(s_avail / 8388608L);
  if (g < 1) g = 1;
  if (g > 32) g = 32;
  if (g >= 8) g &= ~7;  // batches/dispatch multiple of 8 (XCD pin)

  // 1. casts + fused weights
  cast_f32_to_bf16<<<16384, 256, 0, stream>>>(query, Qb, tokE);
  castKT<<<dim3(64, 16, 32), 256, 0, stream>>>(key_, Kb, KbT);
  smallGT<<<dim3(32, 32), 256, 0, stream>>>(Wk, Wq, GT);    // GT[n,c]
  smallW2T<<<dim3(32, 32), 256, 0, stream>>>(Wv, Wo, W2T);  // W2T[e,k]
  wveck<<<512, 256, 0, stream>>>(Wk, bq, wv);
  cveck<<<2, 256, 0, stream>>>(Wo, bv, bo, c2);
  betak<<<16384, 256, 0, stream>>>(Kb, wv, beta);

  // 2. q' = Q @ (Wq Wk^T)   [65536 x 512]
  gemm256<0, 0><<<512, 512, 0, stream>>>(Qb, GT, nullptr, 0, nullptr, nullptr,
                                         qb, 512, 512, 0, 0, 0, 1.0f, 256, 2, 1, 0);

  // 3. attention per group:
  //    E = exp(q'.Kin^T/512 + beta) + row partials ; rinv = 1/rowsum ;
  //    T = E.Kin * rinv / 2048
  for (int b0 = 0; b0 < 32; b0 += g) {
    int bc = (32 - b0 < g) ? (32 - b0) : g;
    u16* Sg = (u16*)Sbase;
    gemm256<0, 1><<<8 * 8 * bc, 512, 0, stream>>>(
        qb + (long)b0 * bstride, Kb + (long)b0 * bstride,
        beta + (long)b0 * 2048, 2048, nullptr, psum, Sg, 2048, 512,
        bstride, bstride, 2048L * 2048, 1.0f / 512.0f, 8, 8, bc, 0);
    rowred<<<(bc * 2048 + 255) / 256, 256, 0, stream>>>(psum, rinv + b0 * 2048,
                                                        bc * 2048);
    gemm256<0, 0><<<8 * 2 * bc, 512, 0, stream>>>(
        Sg, KbT + (long)b0 * bstride, nullptr, 0, rinv + b0 * 2048, nullptr,
        attn + (long)b0 * bstride, 512, 2048,
        2048L * 2048, bstride, bstride, 1.0f / 2048.0f, 8, 2, bc, 1);
  }

  // 4. out = T @ (Wv Wo) + c2   (fp32)
  gemm256<2, 0><<<512, 512, 0, stream>>>(attn, W2T, c2, 0, nullptr, nullptr,
                                         out, 512, 512, 0, 0, 0, 1.0f, 256, 2, 1, 0);
}